// Round 1
// baseline (805.759 us; speedup 1.0000x reference)
//
#include <hip/hip_runtime.h>
#include <math.h>

#define D_ 128
#define K_ 1024
#define N_ 65536
#define DECAY_ 0.99f
#define OMD_ 0.01f
#define EPS_ 1e-5f
#define VQC_ 0.25f

// ---- workspace offsets (in floats) ----
#define WOFF_CODE  0          // int[65536]
#define WOFF_E2    65536      // float[1024]
#define WOFF_CNT   66560      // float[1024]
#define WOFF_ESUM  67584      // float[131072]  (D x K)
#define WOFF_CS    198656     // float[1024]
#define WOFF_SSQ   199680     // float[1]
#define WOFF_ET    200704     // float[131072]  (K x D), 16B aligned

// ---- output offsets (in floats), reference return order ----
#define OOFF_Q     0          // [16,4096,128]
#define OOFF_DIFF  8388608    // scalar
#define OOFF_CODE  8388609    // [16,4096]
#define OOFF_NEMB  8454145    // [128,1024]
#define OOFF_NCS   8585217    // [1024]
#define OOFF_NMEAN 8586241    // [128,1024]

// -------------------------------------------------------------------
// E [D][K] -> Et [K][D]
__global__ void k_transpose(const float* __restrict__ E, float* __restrict__ Et) {
    __shared__ float tile[32][33];
    int k0 = blockIdx.x * 32;
    int d0 = blockIdx.y * 32;
    int tx = threadIdx.x;            // 0..31
    for (int ty = threadIdx.y; ty < 32; ty += 8)
        tile[ty][tx] = E[(d0 + ty) * K_ + (k0 + tx)];
    __syncthreads();
    for (int ty = threadIdx.y; ty < 32; ty += 8)
        Et[(k0 + ty) * D_ + (d0 + tx)] = tile[tx][ty];
}

// e2[k] = sum_d E[d][k]^2  (coalesced over k)
__global__ void k_e2(const float* __restrict__ E, float* __restrict__ e2) {
    int k = blockIdx.x * blockDim.x + threadIdx.x;
    float s = 0.f;
    #pragma unroll 8
    for (int d = 0; d < D_; ++d) { float v = E[d * K_ + k]; s = fmaf(v, v, s); }
    e2[k] = s;
}

// -------------------------------------------------------------------
// argmin_k ( e2[k] - 2 * x.e_k )   [x^2 term is constant per token]
// 64-token x 64-code tiles, 4x4 per-thread register tile,
// XOR-swizzled LDS (float4 granularity) => conflict-free b128 reads.
#define FMA4(ac, av, bv)                 \
    ac = fmaf(av.x, bv.x, ac);           \
    ac = fmaf(av.y, bv.y, ac);           \
    ac = fmaf(av.z, bv.z, ac);           \
    ac = fmaf(av.w, bv.w, ac);

__launch_bounds__(256)
__global__ void k_argmin(const float* __restrict__ x, const float* __restrict__ Et,
                         const float* __restrict__ e2, int* __restrict__ code_i,
                         float* __restrict__ code_f) {
    __shared__ float As[64 * 128];   // 32 KB
    __shared__ float Bs[64 * 128];   // 32 KB
    int tid = threadIdx.x;
    int n0  = blockIdx.x * 64;

    // ---- stage token tile (contiguous 32 KB), swizzled ----
    const float4* xg = (const float4*)(x + (size_t)n0 * D_);
    #pragma unroll
    for (int s = 0; s < 8; ++s) {
        int f4 = tid + 256 * s;
        int t  = f4 >> 5;
        int q  = f4 & 31;
        float4 v = xg[f4];
        *(float4*)(As + t * 128 + 4 * (q ^ (t & 7))) = v;
    }

    int wave = tid >> 6, lane = tid & 63;
    int ty = ((wave >> 1) << 3) + (lane >> 3);   // 0..15 token row
    int kx = ((wave & 1) << 3) + (lane & 7);     // 0..15 code col
    int ta = ty & 7, ka = kx & 7;

    const float* A0 = As + (ty +  0) * 128;
    const float* A1 = As + (ty + 16) * 128;
    const float* A2 = As + (ty + 32) * 128;
    const float* A3 = As + (ty + 48) * 128;
    const float* B0 = Bs + (kx +  0) * 128;
    const float* B1 = Bs + (kx + 16) * 128;
    const float* B2 = Bs + (kx + 32) * 128;
    const float* B3 = Bs + (kx + 48) * 128;

    float bestd[4] = {INFINITY, INFINITY, INFINITY, INFINITY};
    int   besti[4] = {0, 0, 0, 0};

    for (int kc = 0; kc < K_; kc += 64) {
        __syncthreads();   // protect Bs readers of previous chunk (and As staging, 1st iter)
        const float4* eg = (const float4*)(Et + kc * D_);
        #pragma unroll
        for (int s = 0; s < 8; ++s) {
            int f4 = tid + 256 * s;
            int c  = f4 >> 5;
            int q  = f4 & 31;
            float4 v = eg[f4];
            *(float4*)(Bs + c * 128 + 4 * (q ^ (c & 7))) = v;
        }
        __syncthreads();

        float acc[4][4];
        #pragma unroll
        for (int i = 0; i < 4; ++i)
            #pragma unroll
            for (int j = 0; j < 4; ++j) acc[i][j] = 0.f;

        #pragma unroll 4
        for (int d4 = 0; d4 < 32; ++d4) {
            int ca = 4 * (d4 ^ ta);
            int cb = 4 * (d4 ^ ka);
            float4 a0 = *(const float4*)(A0 + ca);
            float4 a1 = *(const float4*)(A1 + ca);
            float4 a2 = *(const float4*)(A2 + ca);
            float4 a3 = *(const float4*)(A3 + ca);
            float4 b0 = *(const float4*)(B0 + cb);
            float4 b1 = *(const float4*)(B1 + cb);
            float4 b2 = *(const float4*)(B2 + cb);
            float4 b3 = *(const float4*)(B3 + cb);
            FMA4(acc[0][0], a0, b0); FMA4(acc[0][1], a0, b1);
            FMA4(acc[0][2], a0, b2); FMA4(acc[0][3], a0, b3);
            FMA4(acc[1][0], a1, b0); FMA4(acc[1][1], a1, b1);
            FMA4(acc[1][2], a1, b2); FMA4(acc[1][3], a1, b3);
            FMA4(acc[2][0], a2, b0); FMA4(acc[2][1], a2, b1);
            FMA4(acc[2][2], a2, b2); FMA4(acc[2][3], a2, b3);
            FMA4(acc[3][0], a3, b0); FMA4(acc[3][1], a3, b1);
            FMA4(acc[3][2], a3, b2); FMA4(acc[3][3], a3, b3);
        }

        // ascending kidx => strict '<' keeps first-min (argmin tie semantics)
        #pragma unroll
        for (int j = 0; j < 4; ++j) {
            int kidx = kc + kx + 16 * j;
            float ek = e2[kidx];
            #pragma unroll
            for (int i = 0; i < 4; ++i) {
                float dist = ek - 2.f * acc[i][j];
                if (dist < bestd[i]) { bestd[i] = dist; besti[i] = kidx; }
            }
        }
    }

    // ---- cross-thread (16-way per token) argmin merge; reuse LDS ----
    __syncthreads();
    float* rd = As;
    int*   ri = (int*)Bs;
    #pragma unroll
    for (int i = 0; i < 4; ++i) {
        int t = ty + 16 * i;
        rd[t * 17 + kx] = bestd[i];
        ri[t * 17 + kx] = besti[i];
    }
    __syncthreads();
    if (tid < 64) {
        float bd = rd[tid * 17];
        int   bi = ri[tid * 17];
        #pragma unroll
        for (int c = 1; c < 16; ++c) {
            float d2 = rd[tid * 17 + c];
            int   i2 = ri[tid * 17 + c];
            if (d2 < bd || (d2 == bd && i2 < bi)) { bd = d2; bi = i2; }
        }
        code_i[n0 + tid] = bi;
        code_f[n0 + tid] = (float)bi;
    }
}

// -------------------------------------------------------------------
// dequant gather + straight-through + diff partial + counts/emb_sum atomics
__launch_bounds__(256)
__global__ void k_gather(const float* __restrict__ x, const float* __restrict__ Et,
                         const int* __restrict__ code_i, float* __restrict__ outq,
                         float* __restrict__ emb_sum, float* __restrict__ counts,
                         float* __restrict__ ssq) {
    int e4 = blockIdx.x * 256 + threadIdx.x;   // float4 index over N*D/4
    int n = e4 >> 5, q = e4 & 31;
    int c = code_i[n];
    float4 xi = ((const float4*)x)[e4];
    float4 qv = ((const float4*)Et)[c * 32 + q];
    float4 qs;  // straight-through: x + (q - x), matching reference rounding
    qs.x = xi.x + (qv.x - xi.x);
    qs.y = xi.y + (qv.y - xi.y);
    qs.z = xi.z + (qv.z - xi.z);
    qs.w = xi.w + (qv.w - xi.w);
    ((float4*)outq)[e4] = qs;
    float dx = qs.x - xi.x, dy = qs.y - xi.y, dz = qs.z - xi.z, dw = qs.w - xi.w;
    float loc = dx * dx + dy * dy + dz * dz + dw * dw;

    int d0 = q * 4;
    atomicAdd(emb_sum + (d0 + 0) * K_ + c, xi.x);
    atomicAdd(emb_sum + (d0 + 1) * K_ + c, xi.y);
    atomicAdd(emb_sum + (d0 + 2) * K_ + c, xi.z);
    atomicAdd(emb_sum + (d0 + 3) * K_ + c, xi.w);
    if (q == 0) atomicAdd(counts + c, 1.0f);

    // block reduction of squared-diff
    #pragma unroll
    for (int off = 32; off > 0; off >>= 1) loc += __shfl_down(loc, off);
    __shared__ float wsum[4];
    if ((threadIdx.x & 63) == 0) wsum[threadIdx.x >> 6] = loc;
    __syncthreads();
    if (threadIdx.x == 0) atomicAdd(ssq, wsum[0] + wsum[1] + wsum[2] + wsum[3]);
}

// -------------------------------------------------------------------
// EMA cluster size, n-reduction, Laplace smoothing, diff finalize
__launch_bounds__(1024)
__global__ void k_stats(const float* __restrict__ cluster_size, const float* __restrict__ counts,
                        const float* __restrict__ ssq, float* __restrict__ out_ncs,
                        float* __restrict__ out_diff, float* __restrict__ cs) {
    int k = threadIdx.x;
    float ncs = cluster_size[k] * DECAY_ + OMD_ * counts[k];
    out_ncs[k] = ncs;
    __shared__ float red[1024];
    red[k] = ncs;
    __syncthreads();
    for (int off = 512; off > 0; off >>= 1) {
        if (k < off) red[k] += red[k + off];
        __syncthreads();
    }
    float n = red[0];
    cs[k] = (ncs + EPS_) / (n + (float)K_ * EPS_) * n;
    if (k == 0) *out_diff = VQC_ * (*ssq) / (float)(N_ * D_);
}

// -------------------------------------------------------------------
// new_embedding_mean = EMA; new_embedding = mean / cs
// (output regions are odd-float offsets -> scalar stores)
__global__ void k_embed(const float* __restrict__ emb_mean_in, const float* __restrict__ emb_sum,
                        const float* __restrict__ cs, float* __restrict__ out_nmean,
                        float* __restrict__ out_nemb) {
    int i = blockIdx.x * 256 + threadIdx.x;   // over D*K
    float nm = emb_mean_in[i] * DECAY_ + OMD_ * emb_sum[i];
    out_nmean[i] = nm;
    out_nemb[i] = nm / cs[i & (K_ - 1)];
}

// -------------------------------------------------------------------
extern "C" void kernel_launch(void* const* d_in, const int* in_sizes, int n_in,
                              void* d_out, int out_size, void* d_ws, size_t ws_size,
                              hipStream_t stream) {
    const float* x   = (const float*)d_in[0];   // [16,4096,128]
    const float* E   = (const float*)d_in[1];   // [128,1024]
    const float* csz = (const float*)d_in[2];   // [1024]
    const float* em  = (const float*)d_in[3];   // [128,1024]
    float* out = (float*)d_out;
    float* W   = (float*)d_ws;

    int*   code_i = (int*)(W + WOFF_CODE);
    float* e2     = W + WOFF_E2;
    float* counts = W + WOFF_CNT;
    float* esum   = W + WOFF_ESUM;
    float* cs     = W + WOFF_CS;
    float* ssq    = W + WOFF_SSQ;
    float* Et     = W + WOFF_ET;

    // zero counts + emb_sum + cs + ssq in one shot (ws is poisoned 0xAA)
    hipMemsetAsync(counts, 0, (WOFF_SSQ + 1 - WOFF_CNT) * sizeof(float), stream);

    k_transpose<<<dim3(32, 4), dim3(32, 8), 0, stream>>>(E, Et);
    k_e2<<<K_ / 256, 256, 0, stream>>>(E, e2);
    k_argmin<<<N_ / 64, 256, 0, stream>>>(x, Et, e2, code_i, out + OOFF_CODE);
    k_gather<<<(N_ * (D_ / 4)) / 256, 256, 0, stream>>>(x, Et, code_i, out + OOFF_Q,
                                                        esum, counts, ssq);
    k_stats<<<1, 1024, 0, stream>>>(csz, counts, ssq, out + OOFF_NCS, out + OOFF_DIFF, cs);
    k_embed<<<(D_ * K_) / 256, 256, 0, stream>>>(em, esum, cs, out + OOFF_NMEAN, out + OOFF_NEMB);
}

// Round 2
// 521.902 us; speedup vs baseline: 1.5439x; 1.5439x over previous
//
#include <hip/hip_runtime.h>
#include <math.h>

#define D_ 128
#define K_ 1024
#define N_ 65536
#define DECAY_ 0.99f
#define OMD_ 0.01f
#define EPS_ 1e-5f
#define VQC_ 0.25f
#define SSPLIT 4

// ---- workspace offsets (in 4-byte elements) ----
#define WOFF_CODE  0          // int[65536]
#define WOFF_E2    65536      // float[1024]
#define WOFF_CNT   66560      // int[1024]
#define WOFF_SSQ   67584      // float[1]   (CNT..SSQ zeroed in one memset)
#define WOFF_BASE  67648      // int[1025]
#define WOFF_CURS  68736      // int[1024]
#define WOFF_ORDER 69760      // int[65536]
#define WOFF_CS    135296     // float[1024]
#define WOFF_ET    136320     // float[131072] (K x D), 16B aligned
#define WOFF_PART  267392     // float[SSPLIT * 131072]
// total ~792K elements (~3.1 MB)

// ---- output offsets (in floats), reference return order ----
#define OOFF_Q     0          // [16,4096,128]
#define OOFF_DIFF  8388608    // scalar
#define OOFF_CODE  8388609    // [16,4096]
#define OOFF_NEMB  8454145    // [128,1024]
#define OOFF_NCS   8585217    // [1024]
#define OOFF_NMEAN 8586241    // [128,1024]

// -------------------------------------------------------------------
// E [D][K] -> Et [K][D]
__global__ void k_transpose(const float* __restrict__ E, float* __restrict__ Et) {
    __shared__ float tile[32][33];
    int k0 = blockIdx.x * 32;
    int d0 = blockIdx.y * 32;
    int tx = threadIdx.x;            // 0..31
    for (int ty = threadIdx.y; ty < 32; ty += 8)
        tile[ty][tx] = E[(d0 + ty) * K_ + (k0 + tx)];
    __syncthreads();
    for (int ty = threadIdx.y; ty < 32; ty += 8)
        Et[(k0 + ty) * D_ + (d0 + tx)] = tile[tx][ty];
}

// e2[k] = sum_d E[d][k]^2  (coalesced over k)
__global__ void k_e2(const float* __restrict__ E, float* __restrict__ e2) {
    int k = blockIdx.x * blockDim.x + threadIdx.x;
    float s = 0.f;
    #pragma unroll 8
    for (int d = 0; d < D_; ++d) { float v = E[d * K_ + k]; s = fmaf(v, v, s); }
    e2[k] = s;
}

// -------------------------------------------------------------------
// argmin_k ( e2[k] - 2 * x.e_k ), + code histogram for the counting sort
#define FMA4(ac, av, bv)                 \
    ac = fmaf(av.x, bv.x, ac);           \
    ac = fmaf(av.y, bv.y, ac);           \
    ac = fmaf(av.z, bv.z, ac);           \
    ac = fmaf(av.w, bv.w, ac);

__launch_bounds__(256)
__global__ void k_argmin(const float* __restrict__ x, const float* __restrict__ Et,
                         const float* __restrict__ e2, int* __restrict__ code_i,
                         float* __restrict__ code_f, int* __restrict__ cnt) {
    __shared__ float As[64 * 128];   // 32 KB
    __shared__ float Bs[64 * 128];   // 32 KB
    int tid = threadIdx.x;
    int n0  = blockIdx.x * 64;

    // ---- stage token tile (contiguous 32 KB), swizzled ----
    const float4* xg = (const float4*)(x + (size_t)n0 * D_);
    #pragma unroll
    for (int s = 0; s < 8; ++s) {
        int f4 = tid + 256 * s;
        int t  = f4 >> 5;
        int q  = f4 & 31;
        float4 v = xg[f4];
        *(float4*)(As + t * 128 + 4 * (q ^ (t & 7))) = v;
    }

    int wave = tid >> 6, lane = tid & 63;
    int ty = ((wave >> 1) << 3) + (lane >> 3);   // 0..15 token row
    int kx = ((wave & 1) << 3) + (lane & 7);     // 0..15 code col
    int ta = ty & 7, ka = kx & 7;

    const float* A0 = As + (ty +  0) * 128;
    const float* A1 = As + (ty + 16) * 128;
    const float* A2 = As + (ty + 32) * 128;
    const float* A3 = As + (ty + 48) * 128;
    const float* B0 = Bs + (kx +  0) * 128;
    const float* B1 = Bs + (kx + 16) * 128;
    const float* B2 = Bs + (kx + 32) * 128;
    const float* B3 = Bs + (kx + 48) * 128;

    float bestd[4] = {INFINITY, INFINITY, INFINITY, INFINITY};
    int   besti[4] = {0, 0, 0, 0};

    for (int kc = 0; kc < K_; kc += 64) {
        __syncthreads();   // protect Bs readers of previous chunk (and As staging, 1st iter)
        const float4* eg = (const float4*)(Et + kc * D_);
        #pragma unroll
        for (int s = 0; s < 8; ++s) {
            int f4 = tid + 256 * s;
            int c  = f4 >> 5;
            int q  = f4 & 31;
            float4 v = eg[f4];
            *(float4*)(Bs + c * 128 + 4 * (q ^ (c & 7))) = v;
        }
        __syncthreads();

        float acc[4][4];
        #pragma unroll
        for (int i = 0; i < 4; ++i)
            #pragma unroll
            for (int j = 0; j < 4; ++j) acc[i][j] = 0.f;

        #pragma unroll 4
        for (int d4 = 0; d4 < 32; ++d4) {
            int ca = 4 * (d4 ^ ta);
            int cb = 4 * (d4 ^ ka);
            float4 a0 = *(const float4*)(A0 + ca);
            float4 a1 = *(const float4*)(A1 + ca);
            float4 a2 = *(const float4*)(A2 + ca);
            float4 a3 = *(const float4*)(A3 + ca);
            float4 b0 = *(const float4*)(B0 + cb);
            float4 b1 = *(const float4*)(B1 + cb);
            float4 b2 = *(const float4*)(B2 + cb);
            float4 b3 = *(const float4*)(B3 + cb);
            FMA4(acc[0][0], a0, b0); FMA4(acc[0][1], a0, b1);
            FMA4(acc[0][2], a0, b2); FMA4(acc[0][3], a0, b3);
            FMA4(acc[1][0], a1, b0); FMA4(acc[1][1], a1, b1);
            FMA4(acc[1][2], a1, b2); FMA4(acc[1][3], a1, b3);
            FMA4(acc[2][0], a2, b0); FMA4(acc[2][1], a2, b1);
            FMA4(acc[2][2], a2, b2); FMA4(acc[2][3], a2, b3);
            FMA4(acc[3][0], a3, b0); FMA4(acc[3][1], a3, b1);
            FMA4(acc[3][2], a3, b2); FMA4(acc[3][3], a3, b3);
        }

        // ascending kidx => strict '<' keeps first-min (argmin tie semantics)
        #pragma unroll
        for (int j = 0; j < 4; ++j) {
            int kidx = kc + kx + 16 * j;
            float ek = e2[kidx];
            #pragma unroll
            for (int i = 0; i < 4; ++i) {
                float dist = ek - 2.f * acc[i][j];
                if (dist < bestd[i]) { bestd[i] = dist; besti[i] = kidx; }
            }
        }
    }

    // ---- cross-thread (16-way per token) argmin merge; reuse LDS ----
    __syncthreads();
    float* rd = As;
    int*   ri = (int*)Bs;
    #pragma unroll
    for (int i = 0; i < 4; ++i) {
        int t = ty + 16 * i;
        rd[t * 17 + kx] = bestd[i];
        ri[t * 17 + kx] = besti[i];
    }
    __syncthreads();
    if (tid < 64) {
        float bd = rd[tid * 17];
        int   bi = ri[tid * 17];
        #pragma unroll
        for (int c = 1; c < 16; ++c) {
            float d2 = rd[tid * 17 + c];
            int   i2 = ri[tid * 17 + c];
            if (d2 < bd || (d2 == bd && i2 < bi)) { bd = d2; bi = i2; }
        }
        code_i[n0 + tid] = bi;
        code_f[n0 + tid] = (float)bi;
        atomicAdd(cnt + bi, 1);
    }
}

// -------------------------------------------------------------------
// exclusive scan of code histogram -> base, cursor
__launch_bounds__(1024)
__global__ void k_scan(const int* __restrict__ cnt, int* __restrict__ base,
                       int* __restrict__ cursor) {
    int k = threadIdx.x;
    __shared__ int sc[1024];
    int c = cnt[k];
    sc[k] = c;
    __syncthreads();
    for (int off = 1; off < 1024; off <<= 1) {
        int v = (k >= off) ? sc[k - off] : 0;
        __syncthreads();
        sc[k] += v;
        __syncthreads();
    }
    int inc = sc[k];
    base[k + 1] = inc;
    cursor[k]   = inc - c;   // exclusive
    if (k == 0) base[0] = 0;
}

// -------------------------------------------------------------------
// dequant gather + straight-through + diff partial + token-index scatter
__launch_bounds__(256)
__global__ void k_gather(const float* __restrict__ x, const float* __restrict__ Et,
                         const int* __restrict__ code_i, float* __restrict__ outq,
                         int* __restrict__ cursor, int* __restrict__ order,
                         float* __restrict__ ssq) {
    int e4 = blockIdx.x * 256 + threadIdx.x;   // float4 index over N*D/4
    int n = e4 >> 5, q = e4 & 31;
    int c = code_i[n];
    float4 xi = ((const float4*)x)[e4];
    float4 qv = ((const float4*)Et)[c * 32 + q];
    float4 qs;  // straight-through: x + (q - x), matching reference rounding
    qs.x = xi.x + (qv.x - xi.x);
    qs.y = xi.y + (qv.y - xi.y);
    qs.z = xi.z + (qv.z - xi.z);
    qs.w = xi.w + (qv.w - xi.w);
    ((float4*)outq)[e4] = qs;
    float dx = qs.x - xi.x, dy = qs.y - xi.y, dz = qs.z - xi.z, dw = qs.w - xi.w;
    float loc = dx * dx + dy * dy + dz * dz + dw * dw;

    if (q == 0) {
        int pos = atomicAdd(cursor + c, 1);
        order[pos] = n;
    }

    // block reduction of squared-diff
    #pragma unroll
    for (int off = 32; off > 0; off >>= 1) loc += __shfl_down(loc, off);
    __shared__ float wsum[4];
    if ((threadIdx.x & 63) == 0) wsum[threadIdx.x >> 6] = loc;
    __syncthreads();
    if (threadIdx.x == 0) atomicAdd(ssq, wsum[0] + wsum[1] + wsum[2] + wsum[3]);
}

// -------------------------------------------------------------------
// segment sum via sorted token lists: block (c, s) sums 1/SSPLIT of code c
__launch_bounds__(128)
__global__ void k_segsum(const float* __restrict__ x, const int* __restrict__ order,
                         const int* __restrict__ base, float* __restrict__ part) {
    int c = blockIdx.x, s = blockIdx.y, d = threadIdx.x;
    int b0 = base[c], b1 = base[c + 1];
    int cnt = b1 - b0;
    int i0 = b0 + (cnt * s) / SSPLIT;
    int i1 = b0 + (cnt * (s + 1)) / SSPLIT;
    float a0 = 0.f, a1 = 0.f, a2 = 0.f, a3 = 0.f;
    int i = i0;
    for (; i + 4 <= i1; i += 4) {
        int n0 = order[i], n1 = order[i + 1], n2 = order[i + 2], n3 = order[i + 3];
        a0 += x[(size_t)n0 * D_ + d];
        a1 += x[(size_t)n1 * D_ + d];
        a2 += x[(size_t)n2 * D_ + d];
        a3 += x[(size_t)n3 * D_ + d];
    }
    for (; i < i1; ++i) a0 += x[(size_t)order[i] * D_ + d];
    part[((size_t)s * K_ + c) * D_ + d] = (a0 + a1) + (a2 + a3);
}

// -------------------------------------------------------------------
// EMA cluster size, n-reduction, Laplace smoothing, diff finalize
__launch_bounds__(1024)
__global__ void k_stats(const float* __restrict__ cluster_size, const int* __restrict__ cnt,
                        const float* __restrict__ ssq, float* __restrict__ out_ncs,
                        float* __restrict__ out_diff, float* __restrict__ cs) {
    int k = threadIdx.x;
    float ncs = cluster_size[k] * DECAY_ + OMD_ * (float)cnt[k];
    out_ncs[k] = ncs;
    __shared__ float red[1024];
    red[k] = ncs;
    __syncthreads();
    for (int off = 512; off > 0; off >>= 1) {
        if (k < off) red[k] += red[k + off];
        __syncthreads();
    }
    float n = red[0];
    cs[k] = (ncs + EPS_) / (n + (float)K_ * EPS_) * n;
    if (k == 0) *out_diff = VQC_ * (*ssq) / (float)(N_ * D_);
}

// -------------------------------------------------------------------
// reduce partials; new_embedding_mean = EMA; new_embedding = mean / cs
__global__ void k_embed(const float* __restrict__ emb_mean_in, const float* __restrict__ part,
                        const float* __restrict__ cs, float* __restrict__ out_nmean,
                        float* __restrict__ out_nemb) {
    int i = blockIdx.x * 256 + threadIdx.x;   // over D*K, layout [D][K]
    int k = i & (K_ - 1);
    int d = i >> 10;
    float es = 0.f;
    #pragma unroll
    for (int s = 0; s < SSPLIT; ++s) es += part[((size_t)s * K_ + k) * D_ + d];
    float nm = emb_mean_in[i] * DECAY_ + OMD_ * es;
    out_nmean[i] = nm;
    out_nemb[i]  = nm / cs[k];
}

// -------------------------------------------------------------------
extern "C" void kernel_launch(void* const* d_in, const int* in_sizes, int n_in,
                              void* d_out, int out_size, void* d_ws, size_t ws_size,
                              hipStream_t stream) {
    const float* x   = (const float*)d_in[0];   // [16,4096,128]
    const float* E   = (const float*)d_in[1];   // [128,1024]
    const float* csz = (const float*)d_in[2];   // [1024]
    const float* em  = (const float*)d_in[3];   // [128,1024]
    float* out = (float*)d_out;
    float* W   = (float*)d_ws;

    int*   code_i = (int*)(W + WOFF_CODE);
    float* e2     = W + WOFF_E2;
    int*   cnt    = (int*)(W + WOFF_CNT);
    float* ssq    = W + WOFF_SSQ;
    int*   base   = (int*)(W + WOFF_BASE);
    int*   cursor = (int*)(W + WOFF_CURS);
    int*   order  = (int*)(W + WOFF_ORDER);
    float* cs     = W + WOFF_CS;
    float* Et     = W + WOFF_ET;
    float* part   = W + WOFF_PART;

    // zero cnt[1024] + ssq[1] (ws is poisoned 0xAA)
    hipMemsetAsync(cnt, 0, 1025 * sizeof(int), stream);

    k_transpose<<<dim3(32, 4), dim3(32, 8), 0, stream>>>(E, Et);
    k_e2<<<K_ / 256, 256, 0, stream>>>(E, e2);
    k_argmin<<<N_ / 64, 256, 0, stream>>>(x, Et, e2, code_i, out + OOFF_CODE, cnt);
    k_scan<<<1, 1024, 0, stream>>>(cnt, base, cursor);
    k_gather<<<(N_ * (D_ / 4)) / 256, 256, 0, stream>>>(x, Et, code_i, out + OOFF_Q,
                                                        cursor, order, ssq);
    k_segsum<<<dim3(K_, SSPLIT), 128, 0, stream>>>(x, order, base, part);
    k_stats<<<1, 1024, 0, stream>>>(csz, cnt, ssq, out + OOFF_NCS, out + OOFF_DIFF, cs);
    k_embed<<<(D_ * K_) / 256, 256, 0, stream>>>(em, part, cs, out + OOFF_NMEAN, out + OOFF_NEMB);
}